// Round 3
// baseline (248.106 us; speedup 1.0000x reference)
//
#include <hip/hip_runtime.h>
#include <cstdint>
#include <cstddef>

// ---------------------------------------------------------------------------
// BNN classifier: 3x binarized conv+BN+sign, avgpool, FC.
// All conv math is exact integer XNOR-popcount on bit-packed +-1 data.
// Scratch lives in __device__ globals (not d_ws) so no assumption on ws_size.
// ---------------------------------------------------------------------------

__device__ uint32_t g_h1p[32 * 224 * 224];   // 6.4 MB: layer1 sign bits, bit=oc
__device__ uint64_t g_h2p[32 * 112 * 112];   // 3.2 MB: layer2 sign bits, bit=oc
__device__ uint32_t g_w1p[32];
__device__ uint32_t g_w2p[576];
__device__ uint64_t g_w3p[1152];
__device__ float    g_inv1[32],  g_sh1[32];
__device__ float    g_inv2[64],  g_sh2[64];
__device__ float    g_inv3[128], g_sh3[128];
__device__ int      g_acc[32 * 128];

// ---------- prep: pack weights to bitmasks, compute BN inv/shift, zero acc --
__global__ void prep_kernel(
    const float* __restrict__ w1, const float* __restrict__ w2, const float* __restrict__ w3,
    const float* __restrict__ g1, const float* __restrict__ b1, const float* __restrict__ m1, const float* __restrict__ v1,
    const float* __restrict__ g2, const float* __restrict__ b2, const float* __restrict__ m2, const float* __restrict__ v2,
    const float* __restrict__ g3, const float* __restrict__ b3, const float* __restrict__ m3, const float* __restrict__ v3)
{
    int tid = blockIdx.x * blockDim.x + threadIdx.x;

    if (tid < 32 * 128) g_acc[tid] = 0;

    if (tid < 32) {  // w1: [32][3][3][3] -> 27-bit mask, bit t = ic*9+ky*3+kx
        uint32_t m = 0;
        for (int t = 0; t < 27; ++t)
            m |= (w1[tid * 27 + t] < 0.0f ? 1u : 0u) << t;
        g_w1p[tid] = m;
    }
    if (tid < 576) { // w2: [64][32][3][3] -> w2p[oc*9+tap], bit=ic
        int oc = tid / 9, tap = tid % 9, ky = tap / 3, kx = tap % 3;
        uint32_t m = 0;
        for (int ic = 0; ic < 32; ++ic)
            m |= (w2[((oc * 32 + ic) * 3 + ky) * 3 + kx] < 0.0f ? 1u : 0u) << ic;
        g_w2p[tid] = m;
    }
    if (tid < 1152) { // w3: [128][64][3][3] -> w3p[oc*9+tap], bit=ic
        int oc = tid / 9, tap = tid % 9, ky = tap / 3, kx = tap % 3;
        uint64_t m = 0;
        for (int ic = 0; ic < 64; ++ic)
            m |= (uint64_t)(w3[((oc * 64 + ic) * 3 + ky) * 3 + kx] < 0.0f ? 1u : 0u) << ic;
        g_w3p[tid] = m;
    }
    // BN params: inv = g / sqrt(v + 1e-5); shift = b - m*inv  (non-fused fp32)
    if (tid < 32) {
        float inv = __fdiv_rn(g1[tid], __fsqrt_rn(__fadd_rn(v1[tid], 1e-5f)));
        g_inv1[tid] = inv;
        g_sh1[tid] = __fsub_rn(b1[tid], __fmul_rn(m1[tid], inv));
    } else if (tid < 96) {
        int c = tid - 32;
        float inv = __fdiv_rn(g2[c], __fsqrt_rn(__fadd_rn(v2[c], 1e-5f)));
        g_inv2[c] = inv;
        g_sh2[c] = __fsub_rn(b2[c], __fmul_rn(m2[c], inv));
    } else if (tid < 224) {
        int c = tid - 96;
        float inv = __fdiv_rn(g3[c], __fsqrt_rn(__fadd_rn(v3[c], 1e-5f)));
        g_inv3[c] = inv;
        g_sh3[c] = __fsub_rn(b3[c], __fmul_rn(m3[c], inv));
    }
}

// ---------- layer 1: fp32 x -> sign bits, 27-tap popcount conv, BN, sign ----
// output: g_h1p[b][y][x] uint32, bit oc = (bn output < 0)
__global__ void layer1_kernel(const float* __restrict__ x)
{
    int idx = blockIdx.x * blockDim.x + threadIdx.x;
    const int total = 32 * 224 * 224;
    if (idx >= total) return;
    int xx = idx % 224;
    int t = idx / 224;
    int yy = t % 224;
    int b = t / 224;

    const float* xb = x + (size_t)b * 3 * 224 * 224;
    uint32_t xmask = 0, vmask = 0;
#pragma unroll
    for (int ky = 0; ky < 3; ++ky) {
        int iy = yy - 1 + ky;
        bool vy = (iy >= 0 && iy < 224);
#pragma unroll
        for (int kx = 0; kx < 3; ++kx) {
            int ix = xx - 1 + kx;
            bool v = vy && (ix >= 0) && (ix < 224);
            if (v) {
                int sp = ky * 3 + kx;
#pragma unroll
                for (int ic = 0; ic < 3; ++ic) {
                    float val = xb[(ic * 224 + iy) * 224 + ix];
                    xmask |= (val < 0.0f ? 1u : 0u) << (ic * 9 + sp);
                    vmask |= 1u << (ic * 9 + sp);
                }
            }
        }
    }
    int nvalid = __popc(vmask);
    uint32_t outw = 0;
#pragma unroll
    for (int oc = 0; oc < 32; ++oc) {
        int mism = __popc((xmask ^ g_w1p[oc]) & vmask);
        int s = nvalid - 2 * mism;
        float y = __fadd_rn(__fmul_rn((float)s, g_inv1[oc]), g_sh1[oc]);
        outw |= (y < 0.0f ? 1u : 0u) << oc;
    }
    g_h1p[idx] = outw;
}

// ---------- layer 2: 32ch packed, stride 2, 64 out ch -> uint64 bits --------
__global__ void layer2_kernel()
{
    __shared__ uint32_t w2s[576];
    __shared__ float invs[64], shs[64];
    for (int i = threadIdx.x; i < 576; i += blockDim.x) w2s[i] = g_w2p[i];
    if (threadIdx.x < 64) { invs[threadIdx.x] = g_inv2[threadIdx.x]; shs[threadIdx.x] = g_sh2[threadIdx.x]; }
    __syncthreads();

    int idx = blockIdx.x * blockDim.x + threadIdx.x;
    const int total = 32 * 112 * 112;
    if (idx >= total) return;
    int ox = idx % 112;
    int t = idx / 112;
    int oy = t % 112;
    int b = t / 112;

    const uint32_t* hb = g_h1p + (size_t)b * 224 * 224;
    uint32_t hw[9];
    bool tv[9];
    int nvt = 0;
#pragma unroll
    for (int ky = 0; ky < 3; ++ky) {
        int iy = 2 * oy - 1 + ky;
        bool vy = (iy >= 0 && iy < 224);
#pragma unroll
        for (int kx = 0; kx < 3; ++kx) {
            int ix = 2 * ox - 1 + kx;
            bool v = vy && (ix >= 0) && (ix < 224);
            int tt = ky * 3 + kx;
            tv[tt] = v;
            nvt += v ? 1 : 0;
            hw[tt] = v ? hb[iy * 224 + ix] : 0u;
        }
    }
    int base = 32 * nvt;
    uint64_t outw = 0;
    for (int oc = 0; oc < 64; ++oc) {
        int s = 0;
#pragma unroll
        for (int tt = 0; tt < 9; ++tt)
            s += tv[tt] ? __popc(hw[tt] ^ w2s[oc * 9 + tt]) : 0;
        int val = base - 2 * s;
        float y = __fadd_rn(__fmul_rn((float)val, invs[oc]), shs[oc]);
        outw |= (uint64_t)(y < 0.0f ? 1u : 0u) << oc;
    }
    g_h2p[idx] = outw;
}

// ---------- layer 3 + avgpool reduce: 64ch packed, stride 2, 128 out ch -----
// accumulates sum of (+-1) over spatial into g_acc[b][oc] via ballot+atomic
__global__ void layer3_kernel()
{
    __shared__ uint64_t w3s[1152];
    __shared__ float invs[128], shs[128];
    for (int i = threadIdx.x; i < 1152; i += blockDim.x) w3s[i] = g_w3p[i];
    for (int i = threadIdx.x; i < 128; i += blockDim.x) { invs[i] = g_inv3[i]; shs[i] = g_sh3[i]; }
    __syncthreads();

    int b = blockIdx.y;
    int pix = blockIdx.x * blockDim.x + threadIdx.x;
    bool valid = pix < 56 * 56;
    int oy = valid ? pix / 56 : 0;
    int ox = valid ? pix % 56 : 0;

    const uint64_t* hb = g_h2p + (size_t)b * 112 * 112;
    uint64_t hw[9];
    bool tv[9];
    int nvt = 0;
#pragma unroll
    for (int ky = 0; ky < 3; ++ky) {
        int iy = 2 * oy - 1 + ky;
        bool vy = (iy >= 0 && iy < 112);
#pragma unroll
        for (int kx = 0; kx < 3; ++kx) {
            int ix = 2 * ox - 1 + kx;
            bool v = valid && vy && (ix >= 0) && (ix < 112);
            int tt = ky * 3 + kx;
            tv[tt] = v;
            nvt += v ? 1 : 0;
            hw[tt] = v ? hb[iy * 112 + ix] : 0ull;
        }
    }
    int base = 64 * nvt;
    int lane = threadIdx.x & 63;
    unsigned long long am = __ballot(valid ? 1 : 0);
    int nact = __popcll(am);

    for (int oc = 0; oc < 128; ++oc) {
        int s = 0;
#pragma unroll
        for (int tt = 0; tt < 9; ++tt)
            s += tv[tt] ? __popcll(hw[tt] ^ w3s[oc * 9 + tt]) : 0;
        int val = base - 2 * s;
        float y = __fadd_rn(__fmul_rn((float)val, invs[oc]), shs[oc]);
        int neg = (valid && y < 0.0f) ? 1 : 0;
        unsigned long long bm = __ballot(neg);
        if (lane == 0) {
            int cneg = __popcll(bm);
            atomicAdd(&g_acc[b * 128 + oc], nact - 2 * cneg);
        }
    }
}

// ---------- final: mean + fc ------------------------------------------------
__global__ void fc_kernel(
    const float* __restrict__ fc_w, const float* __restrict__ fc_b,
    float* __restrict__ out)
{
    int tid = threadIdx.x;
    if (tid >= 64) return;
    int b = tid >> 1, k = tid & 1;
    float s = fc_b[k];
    for (int oc = 0; oc < 128; ++oc) {
        float h = __fdiv_rn((float)g_acc[b * 128 + oc], 3136.0f);
        s = __fadd_rn(s, __fmul_rn(h, fc_w[k * 128 + oc]));
    }
    out[b * 2 + k] = s;
}

// ---------------------------------------------------------------------------
extern "C" void kernel_launch(void* const* d_in, const int* in_sizes, int n_in,
                              void* d_out, int out_size, void* d_ws, size_t ws_size,
                              hipStream_t stream)
{
    const float* x   = (const float*)d_in[0];
    const float* w1  = (const float*)d_in[1];
    const float* w2  = (const float*)d_in[2];
    const float* w3  = (const float*)d_in[3];
    const float* g1  = (const float*)d_in[4];
    const float* b1  = (const float*)d_in[5];
    const float* m1  = (const float*)d_in[6];
    const float* v1  = (const float*)d_in[7];
    const float* g2  = (const float*)d_in[8];
    const float* b2  = (const float*)d_in[9];
    const float* m2  = (const float*)d_in[10];
    const float* v2  = (const float*)d_in[11];
    const float* g3  = (const float*)d_in[12];
    const float* b3  = (const float*)d_in[13];
    const float* m3  = (const float*)d_in[14];
    const float* v3  = (const float*)d_in[15];
    const float* fcw = (const float*)d_in[16];
    const float* fcb = (const float*)d_in[17];
    float* out = (float*)d_out;
    (void)d_ws; (void)ws_size; (void)in_sizes; (void)n_in; (void)out_size;

    // prep: pack weights, BN params, zero acc
    prep_kernel<<<16, 256, 0, stream>>>(w1, w2, w3,
        g1, b1, m1, v1, g2, b2, m2, v2, g3, b3, m3, v3);

    // layer 1
    {
        int total = 32 * 224 * 224;
        layer1_kernel<<<(total + 255) / 256, 256, 0, stream>>>(x);
    }
    // layer 2
    {
        int total = 32 * 112 * 112;
        layer2_kernel<<<(total + 255) / 256, 256, 0, stream>>>();
    }
    // layer 3 + pool reduce
    {
        dim3 grid((56 * 56 + 255) / 256, 32);
        layer3_kernel<<<grid, 256, 0, stream>>>();
    }
    // fc
    fc_kernel<<<1, 64, 0, stream>>>(fcw, fcb, out);
}

// Round 4
// 213.640 us; speedup vs baseline: 1.1613x; 1.1613x over previous
//
#include <hip/hip_runtime.h>
#include <cstdint>
#include <cstddef>

// ---------------------------------------------------------------------------
// BNN classifier: 3x binarized conv+BN+sign, avgpool, FC.
// All conv math is exact integer XNOR-popcount on bit-packed +-1 data.
// R4: oc-parallelism for layers 2/3 (was 16% occupancy, serial 128-oc loop).
// ---------------------------------------------------------------------------

__device__ uint32_t g_h1p[32 * 224 * 224];   // 6.4 MB: layer1 sign bits, bit=oc
__device__ uint32_t g_h2lo[32 * 112 * 112];  // 1.6 MB: layer2 sign bits oc 0..31
__device__ uint32_t g_h2hi[32 * 112 * 112];  // 1.6 MB: layer2 sign bits oc 32..63
__device__ uint32_t g_w1p[32];
__device__ uint32_t g_w2p[576];
__device__ uint64_t g_w3p[1152];
__device__ float    g_inv1[32],  g_sh1[32];
__device__ float    g_inv2[64],  g_sh2[64];
__device__ float    g_inv3[128], g_sh3[128];
__device__ int      g_acc[32 * 128];

// ---------- prep: pack weights to bitmasks, compute BN inv/shift, zero acc --
__global__ void prep_kernel(
    const float* __restrict__ w1, const float* __restrict__ w2, const float* __restrict__ w3,
    const float* __restrict__ g1, const float* __restrict__ b1, const float* __restrict__ m1, const float* __restrict__ v1,
    const float* __restrict__ g2, const float* __restrict__ b2, const float* __restrict__ m2, const float* __restrict__ v2,
    const float* __restrict__ g3, const float* __restrict__ b3, const float* __restrict__ m3, const float* __restrict__ v3)
{
    int tid = blockIdx.x * blockDim.x + threadIdx.x;

    if (tid < 32 * 128) g_acc[tid] = 0;

    if (tid < 32) {  // w1: [32][3][3][3] -> 27-bit mask, bit t = ic*9+ky*3+kx
        uint32_t m = 0;
        for (int t = 0; t < 27; ++t)
            m |= (w1[tid * 27 + t] < 0.0f ? 1u : 0u) << t;
        g_w1p[tid] = m;
    }
    if (tid < 576) { // w2: [64][32][3][3] -> w2p[oc*9+tap], bit=ic
        int oc = tid / 9, tap = tid % 9, ky = tap / 3, kx = tap % 3;
        uint32_t m = 0;
        for (int ic = 0; ic < 32; ++ic)
            m |= (w2[((oc * 32 + ic) * 3 + ky) * 3 + kx] < 0.0f ? 1u : 0u) << ic;
        g_w2p[tid] = m;
    }
    if (tid < 1152) { // w3: [128][64][3][3] -> w3p[oc*9+tap], bit=ic
        int oc = tid / 9, tap = tid % 9, ky = tap / 3, kx = tap % 3;
        uint64_t m = 0;
        for (int ic = 0; ic < 64; ++ic)
            m |= (uint64_t)(w3[((oc * 64 + ic) * 3 + ky) * 3 + kx] < 0.0f ? 1u : 0u) << ic;
        g_w3p[tid] = m;
    }
    // BN params: inv = g / sqrt(v + 1e-5); shift = b - m*inv  (non-fused fp32)
    if (tid < 32) {
        float inv = __fdiv_rn(g1[tid], __fsqrt_rn(__fadd_rn(v1[tid], 1e-5f)));
        g_inv1[tid] = inv;
        g_sh1[tid] = __fsub_rn(b1[tid], __fmul_rn(m1[tid], inv));
    } else if (tid < 96) {
        int c = tid - 32;
        float inv = __fdiv_rn(g2[c], __fsqrt_rn(__fadd_rn(v2[c], 1e-5f)));
        g_inv2[c] = inv;
        g_sh2[c] = __fsub_rn(b2[c], __fmul_rn(m2[c], inv));
    } else if (tid < 224) {
        int c = tid - 96;
        float inv = __fdiv_rn(g3[c], __fsqrt_rn(__fadd_rn(v3[c], 1e-5f)));
        g_inv3[c] = inv;
        g_sh3[c] = __fsub_rn(b3[c], __fmul_rn(m3[c], inv));
    }
}

// ---------- layer 1: fp32 x -> sign bits, 27-tap popcount conv, BN, sign ----
// output: g_h1p[b][y][x] uint32, bit oc = (bn output < 0)
__global__ void layer1_kernel(const float* __restrict__ x)
{
    int idx = blockIdx.x * blockDim.x + threadIdx.x;
    const int total = 32 * 224 * 224;
    if (idx >= total) return;
    int xx = idx % 224;
    int t = idx / 224;
    int yy = t % 224;
    int b = t / 224;

    const float* xb = x + (size_t)b * 3 * 224 * 224;
    uint32_t xmask = 0, vmask = 0;
#pragma unroll
    for (int ky = 0; ky < 3; ++ky) {
        int iy = yy - 1 + ky;
        bool vy = (iy >= 0 && iy < 224);
#pragma unroll
        for (int kx = 0; kx < 3; ++kx) {
            int ix = xx - 1 + kx;
            bool v = vy && (ix >= 0) && (ix < 224);
            if (v) {
                int sp = ky * 3 + kx;
#pragma unroll
                for (int ic = 0; ic < 3; ++ic) {
                    float val = xb[(ic * 224 + iy) * 224 + ix];
                    xmask |= (val < 0.0f ? 1u : 0u) << (ic * 9 + sp);
                    vmask |= 1u << (ic * 9 + sp);
                }
            }
        }
    }
    int nvalid = __popc(vmask);
    uint32_t outw = 0;
#pragma unroll
    for (int oc = 0; oc < 32; ++oc) {
        int mism = __popc((xmask ^ g_w1p[oc]) & vmask);
        int s = nvalid - 2 * mism;
        float y = __fadd_rn(__fmul_rn((float)s, g_inv1[oc]), g_sh1[oc]);
        outw |= (y < 0.0f ? 1u : 0u) << oc;
    }
    g_h1p[idx] = outw;
}

// ---------- layer 2: 32ch packed, stride 2, 64 out ch split lo/hi halves ----
// blockIdx.y = half (0: oc 0..31 -> g_h2lo, 1: oc 32..63 -> g_h2hi)
__global__ void layer2_kernel()
{
    __shared__ uint32_t w2s[32 * 9];
    __shared__ float invs[32], shs[32];
    int half = blockIdx.y;
    for (int i = threadIdx.x; i < 32 * 9; i += blockDim.x) w2s[i] = g_w2p[half * 32 * 9 + i];
    if (threadIdx.x < 32) {
        invs[threadIdx.x] = g_inv2[half * 32 + threadIdx.x];
        shs[threadIdx.x]  = g_sh2[half * 32 + threadIdx.x];
    }
    __syncthreads();

    int idx = blockIdx.x * blockDim.x + threadIdx.x;
    const int total = 32 * 112 * 112;
    if (idx >= total) return;
    int ox = idx % 112;
    int t = idx / 112;
    int oy = t % 112;
    int b = t / 112;

    const uint32_t* hb = g_h1p + (size_t)b * 224 * 224;
    uint32_t hw[9];
    bool tv[9];
    int nvt = 0;
#pragma unroll
    for (int ky = 0; ky < 3; ++ky) {
        int iy = 2 * oy - 1 + ky;
        bool vy = (iy >= 0 && iy < 224);
#pragma unroll
        for (int kx = 0; kx < 3; ++kx) {
            int ix = 2 * ox - 1 + kx;
            bool v = vy && (ix >= 0) && (ix < 224);
            int tt = ky * 3 + kx;
            tv[tt] = v;
            nvt += v ? 1 : 0;
            hw[tt] = v ? hb[iy * 224 + ix] : 0u;
        }
    }
    int base = 32 * nvt;
    uint32_t outw = 0;
    for (int oc = 0; oc < 32; ++oc) {
        int s = 0;
#pragma unroll
        for (int tt = 0; tt < 9; ++tt)
            s += tv[tt] ? __popc(hw[tt] ^ w2s[oc * 9 + tt]) : 0;
        int val = base - 2 * s;
        float y = __fadd_rn(__fmul_rn((float)val, invs[oc]), shs[oc]);
        outw |= (y < 0.0f ? 1u : 0u) << oc;
    }
    if (half == 0) g_h2lo[idx] = outw; else g_h2hi[idx] = outw;
}

// ---------- layer 3 + avgpool reduce: 64ch packed, stride 2, 128 out ch -----
// blockIdx.z = oc quarter (32 ocs each); ballot+atomic into g_acc[b][oc]
__global__ void layer3_kernel()
{
    __shared__ uint64_t w3s[32 * 9];
    __shared__ float invs[32], shs[32];
    int ocq = blockIdx.z;
    for (int i = threadIdx.x; i < 32 * 9; i += blockDim.x) w3s[i] = g_w3p[ocq * 32 * 9 + i];
    if (threadIdx.x < 32) {
        invs[threadIdx.x] = g_inv3[ocq * 32 + threadIdx.x];
        shs[threadIdx.x]  = g_sh3[ocq * 32 + threadIdx.x];
    }
    __syncthreads();

    int b = blockIdx.y;
    int pix = blockIdx.x * blockDim.x + threadIdx.x;
    bool valid = pix < 56 * 56;
    int oy = valid ? pix / 56 : 0;
    int ox = valid ? pix % 56 : 0;

    const uint32_t* hlo = g_h2lo + (size_t)b * 112 * 112;
    const uint32_t* hhi = g_h2hi + (size_t)b * 112 * 112;
    uint64_t hw[9];
    bool tv[9];
    int nvt = 0;
#pragma unroll
    for (int ky = 0; ky < 3; ++ky) {
        int iy = 2 * oy - 1 + ky;
        bool vy = (iy >= 0 && iy < 112);
#pragma unroll
        for (int kx = 0; kx < 3; ++kx) {
            int ix = 2 * ox - 1 + kx;
            bool v = valid && vy && (ix >= 0) && (ix < 112);
            int tt = ky * 3 + kx;
            tv[tt] = v;
            nvt += v ? 1 : 0;
            hw[tt] = v ? ((uint64_t)hlo[iy * 112 + ix] | ((uint64_t)hhi[iy * 112 + ix] << 32)) : 0ull;
        }
    }
    int base = 64 * nvt;
    int lane = threadIdx.x & 63;
    unsigned long long am = __ballot(valid ? 1 : 0);
    int nact = __popcll(am);

    for (int oc = 0; oc < 32; ++oc) {
        int s = 0;
#pragma unroll
        for (int tt = 0; tt < 9; ++tt)
            s += tv[tt] ? __popcll(hw[tt] ^ w3s[oc * 9 + tt]) : 0;
        int val = base - 2 * s;
        float y = __fadd_rn(__fmul_rn((float)val, invs[oc]), shs[oc]);
        int neg = (valid && y < 0.0f) ? 1 : 0;
        unsigned long long bm = __ballot(neg);
        if (lane == 0) {
            int cneg = __popcll(bm);
            atomicAdd(&g_acc[b * 128 + ocq * 32 + oc], nact - 2 * cneg);
        }
    }
}

// ---------- final: mean + fc ------------------------------------------------
__global__ void fc_kernel(
    const float* __restrict__ fc_w, const float* __restrict__ fc_b,
    float* __restrict__ out)
{
    int tid = threadIdx.x;
    if (tid >= 64) return;
    int b = tid >> 1, k = tid & 1;
    float s = fc_b[k];
    for (int oc = 0; oc < 128; ++oc) {
        float h = __fdiv_rn((float)g_acc[b * 128 + oc], 3136.0f);
        s = __fadd_rn(s, __fmul_rn(h, fc_w[k * 128 + oc]));
    }
    out[b * 2 + k] = s;
}

// ---------------------------------------------------------------------------
extern "C" void kernel_launch(void* const* d_in, const int* in_sizes, int n_in,
                              void* d_out, int out_size, void* d_ws, size_t ws_size,
                              hipStream_t stream)
{
    const float* x   = (const float*)d_in[0];
    const float* w1  = (const float*)d_in[1];
    const float* w2  = (const float*)d_in[2];
    const float* w3  = (const float*)d_in[3];
    const float* g1  = (const float*)d_in[4];
    const float* b1  = (const float*)d_in[5];
    const float* m1  = (const float*)d_in[6];
    const float* v1  = (const float*)d_in[7];
    const float* g2  = (const float*)d_in[8];
    const float* b2  = (const float*)d_in[9];
    const float* m2  = (const float*)d_in[10];
    const float* v2  = (const float*)d_in[11];
    const float* g3  = (const float*)d_in[12];
    const float* b3  = (const float*)d_in[13];
    const float* m3  = (const float*)d_in[14];
    const float* v3  = (const float*)d_in[15];
    const float* fcw = (const float*)d_in[16];
    const float* fcb = (const float*)d_in[17];
    float* out = (float*)d_out;
    (void)d_ws; (void)ws_size; (void)in_sizes; (void)n_in; (void)out_size;

    // prep: pack weights, BN params, zero acc
    prep_kernel<<<16, 256, 0, stream>>>(w1, w2, w3,
        g1, b1, m1, v1, g2, b2, m2, v2, g3, b3, m3, v3);

    // layer 1
    {
        int total = 32 * 224 * 224;
        layer1_kernel<<<(total + 255) / 256, 256, 0, stream>>>(x);
    }
    // layer 2: grid.y = lo/hi half of ocs
    {
        int total = 32 * 112 * 112;
        dim3 grid((total + 255) / 256, 2);
        layer2_kernel<<<grid, 256, 0, stream>>>();
    }
    // layer 3 + pool reduce: grid.z = oc quarter
    {
        dim3 grid((56 * 56 + 255) / 256, 32, 4);
        layer3_kernel<<<grid, 256, 0, stream>>>();
    }
    // fc
    fc_kernel<<<1, 64, 0, stream>>>(fcw, fcb, out);
}

// Round 5
// 197.423 us; speedup vs baseline: 1.2567x; 1.0821x over previous
//
#include <hip/hip_runtime.h>
#include <cstdint>
#include <cstddef>

// ---------------------------------------------------------------------------
// BNN classifier: 3x binarized conv+BN+sign, avgpool, FC.
// All conv math is exact integer XNOR-popcount on bit-packed +-1 data.
// R5: weights read as wave-uniform scalar loads from __device__ globals
//     (no LDS staging, no __syncthreads) -> fewer instrs, higher occupancy.
// ---------------------------------------------------------------------------

__device__ uint32_t g_h1p[32 * 224 * 224];   // 6.4 MB: layer1 sign bits, bit=oc
__device__ uint32_t g_h2lo[32 * 112 * 112];  // 1.6 MB: layer2 sign bits oc 0..31
__device__ uint32_t g_h2hi[32 * 112 * 112];  // 1.6 MB: layer2 sign bits oc 32..63
__device__ uint32_t g_w1p[32];
__device__ uint32_t g_w2p[576];
__device__ uint64_t g_w3p[1152];
__device__ float    g_inv1[32],  g_sh1[32];
__device__ float    g_inv2[64],  g_sh2[64];
__device__ float    g_inv3[128], g_sh3[128];
__device__ int      g_acc[32 * 128];

// ---------- prep: pack weights to bitmasks, compute BN inv/shift, zero acc --
__global__ void prep_kernel(
    const float* __restrict__ w1, const float* __restrict__ w2, const float* __restrict__ w3,
    const float* __restrict__ g1, const float* __restrict__ b1, const float* __restrict__ m1, const float* __restrict__ v1,
    const float* __restrict__ g2, const float* __restrict__ b2, const float* __restrict__ m2, const float* __restrict__ v2,
    const float* __restrict__ g3, const float* __restrict__ b3, const float* __restrict__ m3, const float* __restrict__ v3)
{
    int tid = blockIdx.x * blockDim.x + threadIdx.x;

    if (tid < 32 * 128) g_acc[tid] = 0;

    if (tid < 32) {  // w1: [32][3][3][3] -> 27-bit mask, bit t = ic*9+ky*3+kx
        uint32_t m = 0;
        for (int t = 0; t < 27; ++t)
            m |= (w1[tid * 27 + t] < 0.0f ? 1u : 0u) << t;
        g_w1p[tid] = m;
    }
    if (tid < 576) { // w2: [64][32][3][3] -> w2p[oc*9+tap], bit=ic
        int oc = tid / 9, tap = tid % 9, ky = tap / 3, kx = tap % 3;
        uint32_t m = 0;
        for (int ic = 0; ic < 32; ++ic)
            m |= (w2[((oc * 32 + ic) * 3 + ky) * 3 + kx] < 0.0f ? 1u : 0u) << ic;
        g_w2p[tid] = m;
    }
    if (tid < 1152) { // w3: [128][64][3][3] -> w3p[oc*9+tap], bit=ic
        int oc = tid / 9, tap = tid % 9, ky = tap / 3, kx = tap % 3;
        uint64_t m = 0;
        for (int ic = 0; ic < 64; ++ic)
            m |= (uint64_t)(w3[((oc * 64 + ic) * 3 + ky) * 3 + kx] < 0.0f ? 1u : 0u) << ic;
        g_w3p[tid] = m;
    }
    // BN params: inv = g / sqrt(v + 1e-5); shift = b - m*inv  (non-fused fp32)
    if (tid < 32) {
        float inv = __fdiv_rn(g1[tid], __fsqrt_rn(__fadd_rn(v1[tid], 1e-5f)));
        g_inv1[tid] = inv;
        g_sh1[tid] = __fsub_rn(b1[tid], __fmul_rn(m1[tid], inv));
    } else if (tid < 96) {
        int c = tid - 32;
        float inv = __fdiv_rn(g2[c], __fsqrt_rn(__fadd_rn(v2[c], 1e-5f)));
        g_inv2[c] = inv;
        g_sh2[c] = __fsub_rn(b2[c], __fmul_rn(m2[c], inv));
    } else if (tid < 224) {
        int c = tid - 96;
        float inv = __fdiv_rn(g3[c], __fsqrt_rn(__fadd_rn(v3[c], 1e-5f)));
        g_inv3[c] = inv;
        g_sh3[c] = __fsub_rn(b3[c], __fmul_rn(m3[c], inv));
    }
}

// ---------- layer 1: fp32 x -> sign bits, 27-tap popcount conv, BN, sign ----
// output: g_h1p[b][y][x] uint32, bit oc = (bn output < 0)
__global__ void layer1_kernel(const float* __restrict__ x)
{
    int idx = blockIdx.x * blockDim.x + threadIdx.x;
    const int total = 32 * 224 * 224;
    if (idx >= total) return;
    int xx = idx % 224;
    int t = idx / 224;
    int yy = t % 224;
    int b = t / 224;

    const float* xb = x + (size_t)b * 3 * 224 * 224;
    uint32_t xmask = 0, vmask = 0;
#pragma unroll
    for (int ky = 0; ky < 3; ++ky) {
        int iy = yy - 1 + ky;
        bool vy = (iy >= 0 && iy < 224);
#pragma unroll
        for (int kx = 0; kx < 3; ++kx) {
            int ix = xx - 1 + kx;
            bool v = vy && (ix >= 0) && (ix < 224);
            if (v) {
                int sp = ky * 3 + kx;
#pragma unroll
                for (int ic = 0; ic < 3; ++ic) {
                    float val = xb[(ic * 224 + iy) * 224 + ix];
                    xmask |= (val < 0.0f ? 1u : 0u) << (ic * 9 + sp);
                    vmask |= 1u << (ic * 9 + sp);
                }
            }
        }
    }
    int nvalid = __popc(vmask);
    uint32_t outw = 0;
#pragma unroll
    for (int oc = 0; oc < 32; ++oc) {
        int mism = __popc((xmask ^ g_w1p[oc]) & vmask);
        int s = nvalid - 2 * mism;
        float y = __fadd_rn(__fmul_rn((float)s, g_inv1[oc]), g_sh1[oc]);
        outw |= (y < 0.0f ? 1u : 0u) << oc;
    }
    g_h1p[idx] = outw;
}

// ---------- layer 2: 32ch packed, stride 2, 64 out ch split lo/hi halves ----
// blockIdx.y = half (0: oc 0..31 -> g_h2lo, 1: oc 32..63 -> g_h2hi)
// weights/BN read as wave-uniform scalar loads directly from globals
__global__ void layer2_kernel()
{
    int half = blockIdx.y;

    int idx = blockIdx.x * blockDim.x + threadIdx.x;
    const int total = 32 * 112 * 112;
    if (idx >= total) return;
    int ox = idx % 112;
    int t = idx / 112;
    int oy = t % 112;
    int b = t / 112;

    const uint32_t* hb = g_h1p + (size_t)b * 224 * 224;
    uint32_t hw[9];
    bool tv[9];
    int nvt = 0;
#pragma unroll
    for (int ky = 0; ky < 3; ++ky) {
        int iy = 2 * oy - 1 + ky;
        bool vy = (iy >= 0 && iy < 224);
#pragma unroll
        for (int kx = 0; kx < 3; ++kx) {
            int ix = 2 * ox - 1 + kx;
            bool v = vy && (ix >= 0) && (ix < 224);
            int tt = ky * 3 + kx;
            tv[tt] = v;
            nvt += v ? 1 : 0;
            hw[tt] = v ? hb[iy * 224 + ix] : 0u;
        }
    }
    // zero out invalid taps so we can drop per-tap predication in the oc loop
#pragma unroll
    for (int tt = 0; tt < 9; ++tt)
        if (!tv[tt]) hw[tt] = 0u;

    int base = 32 * nvt;
    const uint32_t* wp = g_w2p + half * 32 * 9;
    const float* invp = g_inv2 + half * 32;
    const float* shp  = g_sh2  + half * 32;
    uint32_t outw = 0;
    for (int oc = 0; oc < 32; ++oc) {
        int s = 0;
#pragma unroll
        for (int tt = 0; tt < 9; ++tt) {
            uint32_t w = wp[oc * 9 + tt];           // uniform -> s_load
            s += __popc(hw[tt] ^ (tv[tt] ? w : 0u));
        }
        int val = base - 2 * s;
        float y = __fadd_rn(__fmul_rn((float)val, invp[oc]), shp[oc]);
        outw |= (y < 0.0f ? 1u : 0u) << oc;
    }
    if (half == 0) g_h2lo[idx] = outw; else g_h2hi[idx] = outw;
}

// ---------- layer 3 + avgpool reduce: 64ch packed, stride 2, 128 out ch -----
// blockIdx.z = oc quarter (32 ocs each); ballot+atomic into g_acc[b][oc]
// weights/BN read as wave-uniform scalar loads directly from globals
__global__ void layer3_kernel()
{
    int ocq = blockIdx.z;

    int b = blockIdx.y;
    int pix = blockIdx.x * blockDim.x + threadIdx.x;
    bool valid = pix < 56 * 56;
    int oy = valid ? pix / 56 : 0;
    int ox = valid ? pix % 56 : 0;

    const uint32_t* hlo = g_h2lo + (size_t)b * 112 * 112;
    const uint32_t* hhi = g_h2hi + (size_t)b * 112 * 112;
    uint64_t hw[9];
    bool tv[9];
    int nvt = 0;
#pragma unroll
    for (int ky = 0; ky < 3; ++ky) {
        int iy = 2 * oy - 1 + ky;
        bool vy = (iy >= 0 && iy < 112);
#pragma unroll
        for (int kx = 0; kx < 3; ++kx) {
            int ix = 2 * ox - 1 + kx;
            bool v = valid && vy && (ix >= 0) && (ix < 112);
            int tt = ky * 3 + kx;
            tv[tt] = v;
            nvt += v ? 1 : 0;
            hw[tt] = v ? ((uint64_t)hlo[iy * 112 + ix] | ((uint64_t)hhi[iy * 112 + ix] << 32)) : 0ull;
        }
    }
    int base = 64 * nvt;
    int lane = threadIdx.x & 63;
    unsigned long long am = __ballot(valid ? 1 : 0);
    int nact = __popcll(am);

    const uint64_t* wp = g_w3p + ocq * 32 * 9;
    const float* invp = g_inv3 + ocq * 32;
    const float* shp  = g_sh3  + ocq * 32;
    for (int oc = 0; oc < 32; ++oc) {
        int s = 0;
#pragma unroll
        for (int tt = 0; tt < 9; ++tt) {
            uint64_t w = wp[oc * 9 + tt];           // uniform -> s_load
            s += __popcll(hw[tt] ^ (tv[tt] ? w : 0ull));
        }
        int val = base - 2 * s;
        float y = __fadd_rn(__fmul_rn((float)val, invp[oc]), shp[oc]);
        int neg = (valid && y < 0.0f) ? 1 : 0;
        unsigned long long bm = __ballot(neg);
        if (lane == 0) {
            int cneg = __popcll(bm);
            atomicAdd(&g_acc[b * 128 + ocq * 32 + oc], nact - 2 * cneg);
        }
    }
}

// ---------- final: mean + fc ------------------------------------------------
__global__ void fc_kernel(
    const float* __restrict__ fc_w, const float* __restrict__ fc_b,
    float* __restrict__ out)
{
    int tid = threadIdx.x;
    if (tid >= 64) return;
    int b = tid >> 1, k = tid & 1;
    float s = fc_b[k];
    for (int oc = 0; oc < 128; ++oc) {
        float h = __fdiv_rn((float)g_acc[b * 128 + oc], 3136.0f);
        s = __fadd_rn(s, __fmul_rn(h, fc_w[k * 128 + oc]));
    }
    out[b * 2 + k] = s;
}

// ---------------------------------------------------------------------------
extern "C" void kernel_launch(void* const* d_in, const int* in_sizes, int n_in,
                              void* d_out, int out_size, void* d_ws, size_t ws_size,
                              hipStream_t stream)
{
    const float* x   = (const float*)d_in[0];
    const float* w1  = (const float*)d_in[1];
    const float* w2  = (const float*)d_in[2];
    const float* w3  = (const float*)d_in[3];
    const float* g1  = (const float*)d_in[4];
    const float* b1  = (const float*)d_in[5];
    const float* m1  = (const float*)d_in[6];
    const float* v1  = (const float*)d_in[7];
    const float* g2  = (const float*)d_in[8];
    const float* b2  = (const float*)d_in[9];
    const float* m2  = (const float*)d_in[10];
    const float* v2  = (const float*)d_in[11];
    const float* g3  = (const float*)d_in[12];
    const float* b3  = (const float*)d_in[13];
    const float* m3  = (const float*)d_in[14];
    const float* v3  = (const float*)d_in[15];
    const float* fcw = (const float*)d_in[16];
    const float* fcb = (const float*)d_in[17];
    float* out = (float*)d_out;
    (void)d_ws; (void)ws_size; (void)in_sizes; (void)n_in; (void)out_size;

    // prep: pack weights, BN params, zero acc
    prep_kernel<<<16, 256, 0, stream>>>(w1, w2, w3,
        g1, b1, m1, v1, g2, b2, m2, v2, g3, b3, m3, v3);

    // layer 1
    {
        int total = 32 * 224 * 224;
        layer1_kernel<<<(total + 255) / 256, 256, 0, stream>>>(x);
    }
    // layer 2: grid.y = lo/hi half of ocs
    {
        int total = 32 * 112 * 112;
        dim3 grid((total + 255) / 256, 2);
        layer2_kernel<<<grid, 256, 0, stream>>>();
    }
    // layer 3 + pool reduce: grid.z = oc quarter
    {
        dim3 grid((56 * 56 + 255) / 256, 32, 4);
        layer3_kernel<<<grid, 256, 0, stream>>>();
    }
    // fc
    fc_kernel<<<1, 64, 0, stream>>>(fcw, fcb, out);
}